// Round 5
// baseline (376.595 us; speedup 1.0000x reference)
//
#include <hip/hip_runtime.h>

// ---------------------------------------------------------------------------
// EfficientMultiHeadAttention (L=8192,B=2,E=1024,H=16,ws=256,D=64)
// cvt weights (1 pass) -> 3x proj GEMM (A: fp32 T14 issue-early/write-late
// fused cvt, B: glds; 2-phase double-buffered, BK=64, XOR-swizzled) ->
// vtrans -> window attention -> output GEMM (fp16 A glds 2-phase, f32 out).
// ws layout (72 MB): W16[8MB] | Vp/Ybuf[32MB] | Vt[32MB]; Qp,Kp in d_out.
// ---------------------------------------------------------------------------

typedef _Float16 half8 __attribute__((ext_vector_type(8)));
typedef _Float16 half4 __attribute__((ext_vector_type(4)));
typedef float    f32x4 __attribute__((ext_vector_type(4)));

#define MFMA16(a, b, c) __builtin_amdgcn_mfma_f32_16x16x32_f16((a), (b), (c), 0, 0, 0)

__device__ inline void gload16(const _Float16* g, _Float16* l) {
  __builtin_amdgcn_global_load_lds(
      (const __attribute__((address_space(1))) void*)g,
      (__attribute__((address_space(3))) void*)l, 16, 0, 0);
}

__device__ inline half8 cvt8(float4 a, float4 b) {
  half8 h = {(_Float16)a.x, (_Float16)a.y, (_Float16)a.z, (_Float16)a.w,
             (_Float16)b.x, (_Float16)b.y, (_Float16)b.z, (_Float16)b.w};
  return h;
}

// ---------------- fp32 -> fp16 convert, 4 weight matrices in one launch ----------------
__global__ __launch_bounds__(256) void cvtw_k(const float* __restrict__ s0,
                                              const float* __restrict__ s1,
                                              const float* __restrict__ s2,
                                              const float* __restrict__ s3,
                                              _Float16* __restrict__ d) {
  const float* s = blockIdx.y == 0 ? s0 : blockIdx.y == 1 ? s1 : blockIdx.y == 2 ? s2 : s3;
  _Float16* dst = d + (size_t)blockIdx.y * (1 << 20);
  int i = (blockIdx.x * 256 + threadIdx.x) * 8;
  float4 a = *(const float4*)(s + i);
  float4 b = *(const float4*)(s + i + 4);
  *(half8*)(dst + i) = cvt8(a, b);
}

// ---------------- GEMM: C[m,n] = sum_k A[m,k]*W[n,k] + bias[n] ----------------
// M=16384, N=K=1024. 128x128 tile, BK=64, 4 waves (2x2), 32 mfma/wave/K-step.
// 2-phase double-buffered: stage tile t+1 (issue) -> compute tile t ->
// [A_F32: cvt+ds_write t+1 after MFMA (T14)] -> one barrier. B (and A when
// fp16) via global_load_lds dwordx4, linear LDS dest, inverse-swizzled global
// source; ds_read_b128 with matching XOR -> 2-way (free).
template <int A_F32, int OUT_F32>
__global__ __launch_bounds__(256) void gemm2p_k(const void* __restrict__ A,
                                                const _Float16* __restrict__ Bw,
                                                const float* __restrict__ bias,
                                                void* __restrict__ Cout) {
  constexpr int K = 1024, N = 1024, NT = 16;
  __shared__ alignas(16) _Float16 As[2][128 * 64];
  __shared__ alignas(16) _Float16 Bs[2][128 * 64];
  const int tid = threadIdx.x, lane = tid & 63, wave = tid >> 6;
  const int r15 = lane & 15, g = lane >> 4;
  const int wr = wave >> 1, wc = wave & 1;
  const int m0 = blockIdx.y * 128, n0 = blockIdx.x * 128;

  // staging geometry: chunk q covers rows q*8..q*8+7; lane -> srow = lane>>3.
  // glds path: source k-chunk = (lane&7)^srow, LDS dest linear (lane order).
  // reg path: source k-chunk = lane&7, LDS dest chunk = (lane&7)^srow.
  const int srow = lane >> 3, kc = lane & 7;
  const int scol = (kc ^ srow) * 8;

  f32x4 acc[4][4] = {};

  // ---- prologue: stage tile 0 into buf 0
  if (A_F32) {
#pragma unroll
    for (int i = 0; i < 4; i++) {
      int q = i * 4 + wave;
      const float* s = (const float*)A + (size_t)(m0 + q * 8 + srow) * K + kc * 8;
      float4 f0 = *(const float4*)s, f1 = *(const float4*)(s + 4);
      *(half8*)&As[0][q * 512 + srow * 64 + ((kc ^ srow) * 8)] = cvt8(f0, f1);
    }
  } else {
#pragma unroll
    for (int i = 0; i < 4; i++) {
      int q = i * 4 + wave;
      gload16((const _Float16*)A + (size_t)(m0 + q * 8 + srow) * K + scol, &As[0][q * 512]);
    }
  }
#pragma unroll
  for (int i = 0; i < 4; i++) {
    int q = i * 4 + wave;
    gload16(Bw + (size_t)(n0 + q * 8 + srow) * K + scol, &Bs[0][q * 512]);
  }
  __syncthreads();

  int cur = 0;
  for (int t = 0; t < NT; t++) {
    const int nxt = cur ^ 1;
    const bool pf = (t + 1 < NT);
    float4 fr[8];
    // ---- issue next-tile staging
    if (pf) {
      if (A_F32) {
#pragma unroll
        for (int i = 0; i < 4; i++) {
          int q = i * 4 + wave;
          const float* s =
              (const float*)A + (size_t)(m0 + q * 8 + srow) * K + (t + 1) * 64 + kc * 8;
          fr[i * 2] = *(const float4*)s;
          fr[i * 2 + 1] = *(const float4*)(s + 4);
        }
      } else {
#pragma unroll
        for (int i = 0; i < 4; i++) {
          int q = i * 4 + wave;
          gload16((const _Float16*)A + (size_t)(m0 + q * 8 + srow) * K + (t + 1) * 64 + scol,
                  &As[nxt][q * 512]);
        }
      }
#pragma unroll
      for (int i = 0; i < 4; i++) {
        int q = i * 4 + wave;
        gload16(Bw + (size_t)(n0 + q * 8 + srow) * K + (t + 1) * 64 + scol,
                &Bs[nxt][q * 512]);
      }
    }
    __builtin_amdgcn_sched_barrier(0);  // keep load-issue ahead of compute

    // ---- compute tile t from buf cur
    half8 af[4][2], bf[4][2];
#pragma unroll
    for (int mi = 0; mi < 4; mi++) {
      int row = wr * 64 + mi * 16 + r15;
#pragma unroll
      for (int kk = 0; kk < 2; kk++)
        af[mi][kk] = *(half8*)&As[cur][row * 64 + (((kk * 4 + g) ^ (row & 7)) * 8)];
    }
#pragma unroll
    for (int ni = 0; ni < 4; ni++) {
      int row = wc * 64 + ni * 16 + r15;
#pragma unroll
      for (int kk = 0; kk < 2; kk++)
        bf[ni][kk] = *(half8*)&Bs[cur][row * 64 + (((kk * 4 + g) ^ (row & 7)) * 8)];
    }
#pragma unroll
    for (int kk = 0; kk < 2; kk++)
#pragma unroll
      for (int mi = 0; mi < 4; mi++)
#pragma unroll
        for (int ni = 0; ni < 4; ni++)
          acc[mi][ni] = MFMA16(af[mi][kk], bf[ni][kk], acc[mi][ni]);
    __builtin_amdgcn_sched_barrier(0);  // keep A-write after compute (T14 write-late)

    if (pf && A_F32) {
#pragma unroll
      for (int i = 0; i < 4; i++) {
        int q = i * 4 + wave;
        *(half8*)&As[nxt][q * 512 + srow * 64 + ((kc ^ srow) * 8)] =
            cvt8(fr[i * 2], fr[i * 2 + 1]);
      }
    }
    __syncthreads();
    cur = nxt;
  }

  // epilogue: D layout col(N) = lane&15, row(M) = (lane>>4)*4 + reg
#pragma unroll
  for (int ni = 0; ni < 4; ni++) {
    const int col = n0 + wc * 64 + ni * 16 + r15;
    const float bv = bias[col];
#pragma unroll
    for (int mi = 0; mi < 4; mi++) {
      const int rowb = m0 + wr * 64 + mi * 16 + g * 4;
#pragma unroll
      for (int r = 0; r < 4; r++) {
        float x = acc[mi][ni][r] + bv;
        if (OUT_F32)
          ((float*)Cout)[(size_t)(rowb + r) * N + col] = x;
        else
          ((_Float16*)Cout)[(size_t)(rowb + r) * N + col] = (_Float16)x;
      }
    }
  }
}

// ---------------- V transpose: Vp(L,B,E) -> Vt[(b*512+c)*64 + d][256 k] ----------------
__global__ __launch_bounds__(256) void vtrans_k(const _Float16* __restrict__ Vp,
                                                _Float16* __restrict__ Vt) {
  const int c = blockIdx.x, b = blockIdx.y;
  __shared__ alignas(16) _Float16 Vl[256 * 64];  // [k][d], chunk ^= k&7
  const int tid = threadIdx.x;
  const int l0 = c * 16;
#pragma unroll
  for (int i = 0; i < 8; i++) {
    int q = tid + i * 256;
    int w = q >> 3, ck = q & 7;
    int ls = l0 + (w >> 4), h = w & 15;
    half8 v = *(const half8*)(Vp + (size_t)(ls * 2 + b) * 1024 + h * 64 + ck * 8);
    *(half8*)&Vl[w * 64 + (ck ^ (w & 7)) * 8] = v;
  }
  __syncthreads();
  const int d = tid >> 2, kcq = tid & 3;
  const size_t obase = ((size_t)(b * 512 + c) * 64 + d) * 256 + kcq * 64;
#pragma unroll
  for (int i8 = 0; i8 < 8; i8++) {
    half8 v;
#pragma unroll
    for (int j = 0; j < 8; j++) {
      int k = kcq * 64 + i8 * 8 + j;
      v[j] = Vl[k * 64 + (((d >> 3) ^ (k & 7)) * 8) + (d & 7)];
    }
    *(half8*)(Vt + obase + i8 * 8) = v;
  }
}

// ---------------- window attention ----------------
// 8 waves x 32 q-rows. S^T = mfma(A=K rows, B=Q rows): lane owns one q-row's
// scores (k = m*16 + g*4 + reg). Softmax: in-lane reduce + shfl_xor(16,32).
// P bounced via per-wave LDS slice aliased over dead K tile; PV reads Vt (d-major).
__global__ __launch_bounds__(512) void attn_win_k(const _Float16* __restrict__ Qp,
                                                  const _Float16* __restrict__ Kp,
                                                  const _Float16* __restrict__ Vt,
                                                  _Float16* __restrict__ Y) {
  const int c = blockIdx.x, b = blockIdx.y;
  __shared__ alignas(16) _Float16 Kl[256 * 64];  // [k][d] swz chunk^=k&7; later P
  __shared__ alignas(16) _Float16 Vl[64 * 256];  // [d][k] swz chunk^=((d&7)<<2)
  const int tid = threadIdx.x, lane = tid & 63, wave = tid >> 6;
  const int i15 = lane & 15, g = lane >> 4;
  const int l0 = c * 16;

#pragma unroll
  for (int i = 0; i < 4; i++) {
    int q = tid + i * 512;
    int w = q >> 3, ck = q & 7;
    int ls = l0 + (w >> 4), h = w & 15;
    half8 v = *(const half8*)(Kp + (size_t)(ls * 2 + b) * 1024 + h * 64 + ck * 8);
    *(half8*)&Kl[w * 64 + (ck ^ (w & 7)) * 8] = v;
  }
  const size_t vb0 = (size_t)(b * 512 + c) * 64 * 256;
#pragma unroll
  for (int i = 0; i < 4; i++) {
    int q = tid + i * 512;
    int d = q >> 5, ck = q & 31;
    half8 v = *(const half8*)(Vt + vb0 + (size_t)d * 256 + ck * 8);
    *(half8*)&Vl[d * 256 + (ck ^ ((d & 7) << 2)) * 8] = v;
  }
  half8 qf[2][2];
#pragma unroll
  for (int wf = 0; wf < 2; wf++)
#pragma unroll
    for (int dh = 0; dh < 2; dh++) {
      int ls = l0 + wave * 2 + wf;
      qf[wf][dh] =
          *(const half8*)(Qp + (size_t)(ls * 2 + b) * 1024 + i15 * 64 + dh * 32 + g * 8);
    }
  __syncthreads();

  f32x4 acc[16][2] = {};
#pragma unroll
  for (int m = 0; m < 16; m++) {
    int row = m * 16 + i15;
    half8 a0 = *(half8*)&Kl[row * 64 + ((g) ^ (i15 & 7)) * 8];
    half8 a1 = *(half8*)&Kl[row * 64 + ((4 + g) ^ (i15 & 7)) * 8];
    acc[m][0] = MFMA16(a0, qf[0][0], acc[m][0]);
    acc[m][0] = MFMA16(a1, qf[0][1], acc[m][0]);
    acc[m][1] = MFMA16(a0, qf[1][0], acc[m][1]);
    acc[m][1] = MFMA16(a1, qf[1][1], acc[m][1]);
  }

#pragma unroll
  for (int wf = 0; wf < 2; wf++) {
    float mx = -3.0e38f;
#pragma unroll
    for (int m = 0; m < 16; m++)
#pragma unroll
      for (int r = 0; r < 4; r++) mx = fmaxf(mx, acc[m][wf][r]);
    mx = fmaxf(mx, __shfl_xor(mx, 16, 64));
    mx = fmaxf(mx, __shfl_xor(mx, 32, 64));
    float sum = 0.f;
#pragma unroll
    for (int m = 0; m < 16; m++)
#pragma unroll
      for (int r = 0; r < 4; r++) {
        float e = __expf((acc[m][wf][r] - mx) * 0.125f);
        acc[m][wf][r] = e;
        sum += e;
      }
    sum += __shfl_xor(sum, 16, 64);
    sum += __shfl_xor(sum, 32, 64);
    float inv = 1.f / sum;
#pragma unroll
    for (int m = 0; m < 16; m++)
#pragma unroll
      for (int r = 0; r < 4; r++) acc[m][wf][r] *= inv;
  }
  __syncthreads();

  _Float16* Pw = &Kl[wave * 2048];  // [32 rows][64 k] fp16, chunk ^= row&7
  f32x4 oacc[2][4] = {};
#pragma unroll
  for (int kq = 0; kq < 4; kq++) {
#pragma unroll
    for (int wf = 0; wf < 2; wf++) {
      int rrow = wf * 16 + i15;
#pragma unroll
      for (int ml = 0; ml < 4; ml++) {
        f32x4 pv = acc[kq * 4 + ml][wf];
        half4 h = {(_Float16)pv[0], (_Float16)pv[1], (_Float16)pv[2], (_Float16)pv[3]};
        int ck = ml * 2 + (g >> 1);
        *(half4*)&Pw[rrow * 64 + ((ck ^ (i15 & 7)) * 8) + (g & 1) * 4] = h;
      }
    }
    asm volatile("s_waitcnt lgkmcnt(0)" ::: "memory");
    __builtin_amdgcn_sched_barrier(0);
#pragma unroll
    for (int kfl = 0; kfl < 2; kfl++) {
      half8 pa0 = *(half8*)&Pw[(i15)*64 + (((kfl * 4 + g) ^ (i15 & 7)) * 8)];
      half8 pa1 = *(half8*)&Pw[(16 + i15) * 64 + (((kfl * 4 + g) ^ (i15 & 7)) * 8)];
#pragma unroll
      for (int df = 0; df < 4; df++) {
        int drow = df * 16 + i15;
        half8 vbf =
            *(half8*)&Vl[drow * 256 + (((kq * 8 + kfl * 4 + g) ^ ((i15 & 7) << 2)) * 8)];
        oacc[0][df] = MFMA16(pa0, vbf, oacc[0][df]);
        oacc[1][df] = MFMA16(pa1, vbf, oacc[1][df]);
      }
    }
  }

  const int h2 = c >> 5, n = c & 31;
  const size_t yb = ((size_t)(h2 * 2 + b) * 8192 + (size_t)n * 256) * 64;
#pragma unroll
  for (int wf = 0; wf < 2; wf++)
#pragma unroll
    for (int df = 0; df < 4; df++)
#pragma unroll
      for (int r = 0; r < 4; r++) {
        int w = wave * 32 + wf * 16 + g * 4 + r;
        Y[yb + (size_t)w * 64 + df * 16 + i15] = (_Float16)oacc[wf][df][r];
      }
}

// ---------------- launch ----------------
extern "C" void kernel_launch(void* const* d_in, const int* in_sizes, int n_in,
                              void* d_out, int out_size, void* d_ws, size_t ws_size,
                              hipStream_t stream) {
  const float* query = (const float*)d_in[0];
  const float* key_ = (const float*)d_in[1];
  const float* value = (const float*)d_in[2];
  const float* Wq = (const float*)d_in[3];
  const float* bq = (const float*)d_in[4];
  const float* Wk = (const float*)d_in[5];
  const float* bk = (const float*)d_in[6];
  const float* Wv = (const float*)d_in[7];
  const float* bv = (const float*)d_in[8];
  const float* Wo = (const float*)d_in[9];
  const float* bo = (const float*)d_in[10];

  _Float16* ws = (_Float16*)d_ws;
  _Float16* W16 = ws;                     // 4 x 1M halves (8 MB): q,k,v,o
  _Float16* W16q = W16;
  _Float16* W16k = W16 + (1 << 20);
  _Float16* W16v = W16 + 2 * (1 << 20);
  _Float16* W16o = W16 + 3 * (1 << 20);
  _Float16* Vp = ws + 4 * (1 << 20);      // 16M halves (32 MB): V proj, later Ybuf
  _Float16* Vt = Vp + (1 << 24);          // 16M halves (32 MB)
  _Float16* Ybuf = Vp;                    // alias: Vp dead after vtrans

  _Float16* Qp = (_Float16*)d_out;        // Q,K projections parked in d_out
  _Float16* Kp = Qp + (1 << 24);

  cvtw_k<<<dim3(512, 4), 256, 0, stream>>>(Wq, Wk, Wv, Wo, W16);

  dim3 gg(8, 128), gb(256);
  gemm2p_k<1, 0><<<gg, gb, 0, stream>>>((const void*)query, W16q, bq, (void*)Qp);
  gemm2p_k<1, 0><<<gg, gb, 0, stream>>>((const void*)key_, W16k, bk, (void*)Kp);
  gemm2p_k<1, 0><<<gg, gb, 0, stream>>>((const void*)value, W16v, bv, (void*)Vp);

  vtrans_k<<<dim3(512, 2), 256, 0, stream>>>(Vp, Vt);
  attn_win_k<<<dim3(512, 2), 512, 0, stream>>>(Qp, Kp, Vt, Ybuf);

  gemm2p_k<0, 1><<<gg, gb, 0, stream>>>((const void*)Ybuf, W16o, bo, d_out);

  (void)in_sizes; (void)n_in; (void)out_size; (void)ws_size;
}

// Round 6
// 315.309 us; speedup vs baseline: 1.1944x; 1.1944x over previous
//
#include <hip/hip_runtime.h>

// ---------------------------------------------------------------------------
// EfficientMultiHeadAttention (L=8192,B=2,E=1024,H=16,ws=256,D=64)
// cvt weights (1 pass) -> merged 3x proj GEMM (A: fp32 T14 issue-early/
// write-late fused cvt, B: glds; 2-phase double-buffered, BK=64, XOR-swizzled)
// -> vtrans -> window attention -> output GEMM (fp16 A glds 2-phase, f32 out).
// Grid (x=m,y=n[,z=qkv]): XCD = m%8 -> all n-blocks of an A-panel share L2.
// ws layout (72 MB): W16[8MB] | Vp/Ybuf[32MB] | Vt[32MB]; Qp,Kp in d_out.
// ---------------------------------------------------------------------------

typedef _Float16 half8 __attribute__((ext_vector_type(8)));
typedef _Float16 half4 __attribute__((ext_vector_type(4)));
typedef float    f32x4 __attribute__((ext_vector_type(4)));

#define MFMA16(a, b, c) __builtin_amdgcn_mfma_f32_16x16x32_f16((a), (b), (c), 0, 0, 0)

__device__ inline void gload16(const _Float16* g, _Float16* l) {
  __builtin_amdgcn_global_load_lds(
      (const __attribute__((address_space(1))) void*)g,
      (__attribute__((address_space(3))) void*)l, 16, 0, 0);
}

__device__ inline half8 cvt8(float4 a, float4 b) {
  half8 h = {(_Float16)a.x, (_Float16)a.y, (_Float16)a.z, (_Float16)a.w,
             (_Float16)b.x, (_Float16)b.y, (_Float16)b.z, (_Float16)b.w};
  return h;
}

// ---------------- fp32 -> fp16 convert, 4 weight matrices in one launch ----------------
__global__ __launch_bounds__(256) void cvtw_k(const float* __restrict__ s0,
                                              const float* __restrict__ s1,
                                              const float* __restrict__ s2,
                                              const float* __restrict__ s3,
                                              _Float16* __restrict__ d) {
  const float* s = blockIdx.y == 0 ? s0 : blockIdx.y == 1 ? s1 : blockIdx.y == 2 ? s2 : s3;
  _Float16* dst = d + (size_t)blockIdx.y * (1 << 20);
  int i = (blockIdx.x * 256 + threadIdx.x) * 8;
  float4 a = *(const float4*)(s + i);
  float4 b = *(const float4*)(s + i + 4);
  *(half8*)(dst + i) = cvt8(a, b);
}

// ---------------- GEMM body: C[m,n] = sum_k A[m,k]*W[n,k] + bias[n] ----------------
// M=16384, N=K=1024. 128x128 tile, BK=64, 4 waves (2x2), 32 mfma/wave/K-step.
// 2-phase double-buffered: issue tile t+1 staging -> compute tile t ->
// [A_F32: cvt+ds_write t+1 after MFMA (T14 write-late)] -> one barrier.
// glds: linear LDS dest, inverse-swizzled global source (chunk ^= row&7);
// ds_read_b128 with matching XOR -> 2-way (free).
template <int A_F32, int OUT_F32>
__device__ __attribute__((always_inline)) void gemm_body(
    const void* __restrict__ A, const _Float16* __restrict__ Bw,
    const float* __restrict__ bias, void* __restrict__ Cout, int m0, int n0) {
  constexpr int K = 1024, N = 1024, NT = 16;
  __shared__ alignas(16) _Float16 As[2][128 * 64];
  __shared__ alignas(16) _Float16 Bs[2][128 * 64];
  const int tid = threadIdx.x, lane = tid & 63, wave = tid >> 6;
  const int r15 = lane & 15, g = lane >> 4;
  const int wr = wave >> 1, wc = wave & 1;

  const int srow = lane >> 3, kc = lane & 7;
  const int scol = (kc ^ srow) * 8;

  f32x4 acc[4][4] = {};

  // ---- prologue: stage tile 0 into buf 0
  if (A_F32) {
#pragma unroll
    for (int i = 0; i < 4; i++) {
      int q = i * 4 + wave;
      const float* s = (const float*)A + (size_t)(m0 + q * 8 + srow) * K + kc * 8;
      float4 f0 = *(const float4*)s, f1 = *(const float4*)(s + 4);
      *(half8*)&As[0][q * 512 + srow * 64 + ((kc ^ srow) * 8)] = cvt8(f0, f1);
    }
  } else {
#pragma unroll
    for (int i = 0; i < 4; i++) {
      int q = i * 4 + wave;
      gload16((const _Float16*)A + (size_t)(m0 + q * 8 + srow) * K + scol, &As[0][q * 512]);
    }
  }
#pragma unroll
  for (int i = 0; i < 4; i++) {
    int q = i * 4 + wave;
    gload16(Bw + (size_t)(n0 + q * 8 + srow) * K + scol, &Bs[0][q * 512]);
  }
  __syncthreads();

  int cur = 0;
  for (int t = 0; t < NT; t++) {
    const int nxt = cur ^ 1;
    const bool pf = (t + 1 < NT);
    float4 fr[8];
    // ---- issue next-tile staging
    if (pf) {
      if (A_F32) {
#pragma unroll
        for (int i = 0; i < 4; i++) {
          int q = i * 4 + wave;
          const float* s =
              (const float*)A + (size_t)(m0 + q * 8 + srow) * K + (t + 1) * 64 + kc * 8;
          fr[i * 2] = *(const float4*)s;
          fr[i * 2 + 1] = *(const float4*)(s + 4);
        }
      } else {
#pragma unroll
        for (int i = 0; i < 4; i++) {
          int q = i * 4 + wave;
          gload16((const _Float16*)A + (size_t)(m0 + q * 8 + srow) * K + (t + 1) * 64 + scol,
                  &As[nxt][q * 512]);
        }
      }
#pragma unroll
      for (int i = 0; i < 4; i++) {
        int q = i * 4 + wave;
        gload16(Bw + (size_t)(n0 + q * 8 + srow) * K + (t + 1) * 64 + scol,
                &Bs[nxt][q * 512]);
      }
    }
    __builtin_amdgcn_sched_barrier(0);  // keep load-issue ahead of compute

    // ---- compute tile t from buf cur
    half8 af[4][2], bf[4][2];
#pragma unroll
    for (int mi = 0; mi < 4; mi++) {
      int row = wr * 64 + mi * 16 + r15;
#pragma unroll
      for (int kk = 0; kk < 2; kk++)
        af[mi][kk] = *(half8*)&As[cur][row * 64 + (((kk * 4 + g) ^ (row & 7)) * 8)];
    }
#pragma unroll
    for (int ni = 0; ni < 4; ni++) {
      int row = wc * 64 + ni * 16 + r15;
#pragma unroll
      for (int kk = 0; kk < 2; kk++)
        bf[ni][kk] = *(half8*)&Bs[cur][row * 64 + (((kk * 4 + g) ^ (row & 7)) * 8)];
    }
#pragma unroll
    for (int kk = 0; kk < 2; kk++)
#pragma unroll
      for (int mi = 0; mi < 4; mi++)
#pragma unroll
        for (int ni = 0; ni < 4; ni++)
          acc[mi][ni] = MFMA16(af[mi][kk], bf[ni][kk], acc[mi][ni]);
    __builtin_amdgcn_sched_barrier(0);  // keep A-write after compute (T14 write-late)

    if (pf && A_F32) {
#pragma unroll
      for (int i = 0; i < 4; i++) {
        int q = i * 4 + wave;
        *(half8*)&As[nxt][q * 512 + srow * 64 + ((kc ^ srow) * 8)] =
            cvt8(fr[i * 2], fr[i * 2 + 1]);
      }
    }
    __syncthreads();
    cur = nxt;
  }

  // epilogue: D layout col(N) = lane&15, row(M) = (lane>>4)*4 + reg
#pragma unroll
  for (int ni = 0; ni < 4; ni++) {
    const int col = n0 + wc * 64 + ni * 16 + r15;
    const float bv = bias[col];
#pragma unroll
    for (int mi = 0; mi < 4; mi++) {
      const int rowb = m0 + wr * 64 + mi * 16 + g * 4;
#pragma unroll
      for (int r = 0; r < 4; r++) {
        float x = acc[mi][ni][r] + bv;
        if (OUT_F32)
          ((float*)Cout)[(size_t)(rowb + r) * N + col] = x;
        else
          ((_Float16*)Cout)[(size_t)(rowb + r) * N + col] = (_Float16)x;
      }
    }
  }
}

// merged q/k/v projection: blockIdx.z selects input/weight/bias/output
__global__ __launch_bounds__(256) void gemm_proj_k(
    const float* __restrict__ Aq, const float* __restrict__ Ak,
    const float* __restrict__ Av, const _Float16* __restrict__ W16,
    const float* __restrict__ bq, const float* __restrict__ bk,
    const float* __restrict__ bv, _Float16* __restrict__ Oq,
    _Float16* __restrict__ Ok, _Float16* __restrict__ Ov) {
  const int z = blockIdx.z;
  const float* A = z == 0 ? Aq : z == 1 ? Ak : Av;
  const float* bias = z == 0 ? bq : z == 1 ? bk : bv;
  _Float16* out = z == 0 ? Oq : z == 1 ? Ok : Ov;
  gemm_body<1, 0>((const void*)A, W16 + ((size_t)z << 20), bias, (void*)out,
                  blockIdx.x * 128, blockIdx.y * 128);
}

__global__ __launch_bounds__(256) void gemm_out_k(const _Float16* __restrict__ A,
                                                  const _Float16* __restrict__ Bw,
                                                  const float* __restrict__ bias,
                                                  float* __restrict__ Cout) {
  gemm_body<0, 1>((const void*)A, Bw, bias, (void*)Cout, blockIdx.x * 128,
                  blockIdx.y * 128);
}

// ---------------- V transpose: Vp(L,B,E) -> Vt[(b*512+c)*64 + d][256 k] ----------------
__global__ __launch_bounds__(256) void vtrans_k(const _Float16* __restrict__ Vp,
                                                _Float16* __restrict__ Vt) {
  const int c = blockIdx.x, b = blockIdx.y;
  __shared__ alignas(16) _Float16 Vl[256 * 64];  // [k][d], chunk ^= k&7
  const int tid = threadIdx.x;
  const int l0 = c * 16;
#pragma unroll
  for (int i = 0; i < 8; i++) {
    int q = tid + i * 256;
    int w = q >> 3, ck = q & 7;
    int ls = l0 + (w >> 4), h = w & 15;
    half8 v = *(const half8*)(Vp + (size_t)(ls * 2 + b) * 1024 + h * 64 + ck * 8);
    *(half8*)&Vl[w * 64 + (ck ^ (w & 7)) * 8] = v;
  }
  __syncthreads();
  const int d = tid >> 2, kcq = tid & 3;
  const size_t obase = ((size_t)(b * 512 + c) * 64 + d) * 256 + kcq * 64;
#pragma unroll
  for (int i8 = 0; i8 < 8; i8++) {
    half8 v;
#pragma unroll
    for (int j = 0; j < 8; j++) {
      int k = kcq * 64 + i8 * 8 + j;
      v[j] = Vl[k * 64 + (((d >> 3) ^ (k & 7)) * 8) + (d & 7)];
    }
    *(half8*)(Vt + obase + i8 * 8) = v;
  }
}

// ---------------- window attention ----------------
__global__ __launch_bounds__(512) void attn_win_k(const _Float16* __restrict__ Qp,
                                                  const _Float16* __restrict__ Kp,
                                                  const _Float16* __restrict__ Vt,
                                                  _Float16* __restrict__ Y) {
  const int c = blockIdx.x, b = blockIdx.y;
  __shared__ alignas(16) _Float16 Kl[256 * 64];  // [k][d] swz chunk^=k&7; later P
  __shared__ alignas(16) _Float16 Vl[64 * 256];  // [d][k] swz chunk^=((d&7)<<2)
  const int tid = threadIdx.x, lane = tid & 63, wave = tid >> 6;
  const int i15 = lane & 15, g = lane >> 4;
  const int l0 = c * 16;

#pragma unroll
  for (int i = 0; i < 4; i++) {
    int q = tid + i * 512;
    int w = q >> 3, ck = q & 7;
    int ls = l0 + (w >> 4), h = w & 15;
    half8 v = *(const half8*)(Kp + (size_t)(ls * 2 + b) * 1024 + h * 64 + ck * 8);
    *(half8*)&Kl[w * 64 + (ck ^ (w & 7)) * 8] = v;
  }
  const size_t vb0 = (size_t)(b * 512 + c) * 64 * 256;
#pragma unroll
  for (int i = 0; i < 4; i++) {
    int q = tid + i * 512;
    int d = q >> 5, ck = q & 31;
    half8 v = *(const half8*)(Vt + vb0 + (size_t)d * 256 + ck * 8);
    *(half8*)&Vl[d * 256 + (ck ^ ((d & 7) << 2)) * 8] = v;
  }
  half8 qf[2][2];
#pragma unroll
  for (int wf = 0; wf < 2; wf++)
#pragma unroll
    for (int dh = 0; dh < 2; dh++) {
      int ls = l0 + wave * 2 + wf;
      qf[wf][dh] =
          *(const half8*)(Qp + (size_t)(ls * 2 + b) * 1024 + i15 * 64 + dh * 32 + g * 8);
    }
  __syncthreads();

  f32x4 acc[16][2] = {};
#pragma unroll
  for (int m = 0; m < 16; m++) {
    int row = m * 16 + i15;
    half8 a0 = *(half8*)&Kl[row * 64 + ((g) ^ (i15 & 7)) * 8];
    half8 a1 = *(half8*)&Kl[row * 64 + ((4 + g) ^ (i15 & 7)) * 8];
    acc[m][0] = MFMA16(a0, qf[0][0], acc[m][0]);
    acc[m][0] = MFMA16(a1, qf[0][1], acc[m][0]);
    acc[m][1] = MFMA16(a0, qf[1][0], acc[m][1]);
    acc[m][1] = MFMA16(a1, qf[1][1], acc[m][1]);
  }

#pragma unroll
  for (int wf = 0; wf < 2; wf++) {
    float mx = -3.0e38f;
#pragma unroll
    for (int m = 0; m < 16; m++)
#pragma unroll
      for (int r = 0; r < 4; r++) mx = fmaxf(mx, acc[m][wf][r]);
    mx = fmaxf(mx, __shfl_xor(mx, 16, 64));
    mx = fmaxf(mx, __shfl_xor(mx, 32, 64));
    float sum = 0.f;
#pragma unroll
    for (int m = 0; m < 16; m++)
#pragma unroll
      for (int r = 0; r < 4; r++) {
        float e = __expf((acc[m][wf][r] - mx) * 0.125f);
        acc[m][wf][r] = e;
        sum += e;
      }
    sum += __shfl_xor(sum, 16, 64);
    sum += __shfl_xor(sum, 32, 64);
    float inv = 1.f / sum;
#pragma unroll
    for (int m = 0; m < 16; m++)
#pragma unroll
      for (int r = 0; r < 4; r++) acc[m][wf][r] *= inv;
  }
  __syncthreads();

  _Float16* Pw = &Kl[wave * 2048];  // [32 rows][64 k] fp16, chunk ^= row&7
  f32x4 oacc[2][4] = {};
#pragma unroll
  for (int kq = 0; kq < 4; kq++) {
#pragma unroll
    for (int wf = 0; wf < 2; wf++) {
      int rrow = wf * 16 + i15;
#pragma unroll
      for (int ml = 0; ml < 4; ml++) {
        f32x4 pv = acc[kq * 4 + ml][wf];
        half4 h = {(_Float16)pv[0], (_Float16)pv[1], (_Float16)pv[2], (_Float16)pv[3]};
        int ck = ml * 2 + (g >> 1);
        *(half4*)&Pw[rrow * 64 + ((ck ^ (i15 & 7)) * 8) + (g & 1) * 4] = h;
      }
    }
    asm volatile("s_waitcnt lgkmcnt(0)" ::: "memory");
    __builtin_amdgcn_sched_barrier(0);
#pragma unroll
    for (int kfl = 0; kfl < 2; kfl++) {
      half8 pa0 = *(half8*)&Pw[(i15)*64 + (((kfl * 4 + g) ^ (i15 & 7)) * 8)];
      half8 pa1 = *(half8*)&Pw[(16 + i15) * 64 + (((kfl * 4 + g) ^ (i15 & 7)) * 8)];
#pragma unroll
      for (int df = 0; df < 4; df++) {
        int drow = df * 16 + i15;
        half8 vbf =
            *(half8*)&Vl[drow * 256 + (((kq * 8 + kfl * 4 + g) ^ ((i15 & 7) << 2)) * 8)];
        oacc[0][df] = MFMA16(pa0, vbf, oacc[0][df]);
        oacc[1][df] = MFMA16(pa1, vbf, oacc[1][df]);
      }
    }
  }

  const int h2 = c >> 5, n = c & 31;
  const size_t yb = ((size_t)(h2 * 2 + b) * 8192 + (size_t)n * 256) * 64;
#pragma unroll
  for (int wf = 0; wf < 2; wf++)
#pragma unroll
    for (int df = 0; df < 4; df++)
#pragma unroll
      for (int r = 0; r < 4; r++) {
        int w = wave * 32 + wf * 16 + g * 4 + r;
        Y[yb + (size_t)w * 64 + df * 16 + i15] = (_Float16)oacc[wf][df][r];
      }
}

// ---------------- launch ----------------
extern "C" void kernel_launch(void* const* d_in, const int* in_sizes, int n_in,
                              void* d_out, int out_size, void* d_ws, size_t ws_size,
                              hipStream_t stream) {
  const float* query = (const float*)d_in[0];
  const float* key_ = (const float*)d_in[1];
  const float* value = (const float*)d_in[2];
  const float* Wq = (const float*)d_in[3];
  const float* bq = (const float*)d_in[4];
  const float* Wk = (const float*)d_in[5];
  const float* bk = (const float*)d_in[6];
  const float* Wv = (const float*)d_in[7];
  const float* bv = (const float*)d_in[8];
  const float* Wo = (const float*)d_in[9];
  const float* bo = (const float*)d_in[10];

  _Float16* ws = (_Float16*)d_ws;
  _Float16* W16 = ws;                     // 4 x 1M halves (8 MB): q,k,v,o
  _Float16* W16o = W16 + 3 * (1 << 20);
  _Float16* Vp = ws + 4 * (1 << 20);      // 16M halves (32 MB): V proj, later Ybuf
  _Float16* Vt = Vp + (1 << 24);          // 16M halves (32 MB)
  _Float16* Ybuf = Vp;                    // alias: Vp dead after vtrans

  _Float16* Qp = (_Float16*)d_out;        // Q,K projections parked in d_out
  _Float16* Kp = Qp + (1 << 24);

  cvtw_k<<<dim3(512, 4), 256, 0, stream>>>(Wq, Wk, Wv, Wo, W16);

  gemm_proj_k<<<dim3(128, 8, 3), 256, 0, stream>>>(query, key_, value, W16, bq, bk, bv,
                                                   Qp, Kp, Vp);

  vtrans_k<<<dim3(512, 2), 256, 0, stream>>>(Vp, Vt);
  attn_win_k<<<dim3(512, 2), 512, 0, stream>>>(Qp, Kp, Vt, Ybuf);

  gemm_out_k<<<dim3(128, 8), 256, 0, stream>>>(Ybuf, W16o, bo, (float*)d_out);

  (void)in_sizes; (void)n_in; (void)out_size; (void)ws_size;
}

// Round 7
// 255.023 us; speedup vs baseline: 1.4767x; 1.2364x over previous
//
#include <hip/hip_runtime.h>

// ---------------------------------------------------------------------------
// EfficientMultiHeadAttention (L=8192,B=2,E=1024,H=16,ws=256,D=64)
// cvt weights -> merged 3x proj GEMM + output GEMM on a 256x256 8-phase
// counted-vmcnt template (BK=64, K-split halves, XOR-swizzled LDS, setprio)
// -> vtrans -> window attention.
// proj: A fp32 reg-staged (issue phases 0/1, cvt+ds_write phases 2/3);
// out:  A fp16 via global_load_lds. B always global_load_lds.
// Grid (x=m,y=n[,z]): XCD = m%8 -> n-blocks of an A-panel share an XCD L2.
// ---------------------------------------------------------------------------

typedef _Float16 half8 __attribute__((ext_vector_type(8)));
typedef _Float16 half4 __attribute__((ext_vector_type(4)));
typedef float    f32x4 __attribute__((ext_vector_type(4)));

#define MFMA16(a, b, c) __builtin_amdgcn_mfma_f32_16x16x32_f16((a), (b), (c), 0, 0, 0)
#define VM(n) asm volatile("s_waitcnt vmcnt(" #n ")" ::: "memory")
#define SCHED0 __builtin_amdgcn_sched_barrier(0)
#define LGKM0 do { asm volatile("s_waitcnt lgkmcnt(0)" ::: "memory"); SCHED0; } while (0)
#define BARW do { __builtin_amdgcn_s_barrier(); SCHED0; } while (0)

__device__ inline void gload16(const _Float16* g, _Float16* l) {
  __builtin_amdgcn_global_load_lds(
      (const __attribute__((address_space(1))) void*)g,
      (__attribute__((address_space(3))) void*)l, 16, 0, 0);
}

__device__ inline half8 cvt8(float4 a, float4 b) {
  half8 h = {(_Float16)a.x, (_Float16)a.y, (_Float16)a.z, (_Float16)a.w,
             (_Float16)b.x, (_Float16)b.y, (_Float16)b.z, (_Float16)b.w};
  return h;
}

// ---------------- fp32 -> fp16 convert, 4 weight matrices ----------------
__global__ __launch_bounds__(256) void cvtw_k(const float* __restrict__ s0,
                                              const float* __restrict__ s1,
                                              const float* __restrict__ s2,
                                              const float* __restrict__ s3,
                                              _Float16* __restrict__ d) {
  const float* s = blockIdx.y == 0 ? s0 : blockIdx.y == 1 ? s1 : blockIdx.y == 2 ? s2 : s3;
  _Float16* dst = d + (size_t)blockIdx.y * (1 << 20);
  int i = (blockIdx.x * 256 + threadIdx.x) * 8;
  float4 a = *(const float4*)(s + i);
  float4 b = *(const float4*)(s + i + 4);
  *(half8*)(dst + i) = cvt8(a, b);
}

// ---------------- 256x256 8-phase GEMM body ----------------
// C[m,n] = sum_k A[m,k]*W[n,k] + bias[n]; M=16384, N=K=1024, BK=64, NT=16.
// 8 waves (wr=wave>>2 in {0,1}: 128 rows; wc=wave&3: 64 cols). 128KB LDS:
// A/B x 2buf x 2 K-halves, each half 256rows x 32k fp16 = 16KB, staged
// linearly (512thr x 2x16B) with inverse-swizzled source; reads XOR-swizzle
// within 128B pseudo-rows (2 rows of 32k). Per tile 4 phases (kk,mh):
// counted vmcnt keeps 4-8 loads in flight; one barrier per K-half.
template <int A_F32, int OUT_F32>
__device__ __attribute__((always_inline)) void gemm8p_body(
    const void* __restrict__ A, const _Float16* __restrict__ Bw,
    const float* __restrict__ bias, void* __restrict__ Cout) {
  constexpr int K = 1024, NN = 1024, NT = 16;
  __shared__ alignas(16) _Float16 SH[65536];  // A:[0,32768) B:[32768,65536)
  const int tid = threadIdx.x, lane = tid & 63, wave = tid >> 6;
  const int r15 = lane & 15, g = lane >> 4;
  const int wr = wave >> 2, wc = wave & 3;
  const int m0 = blockIdx.x * 256, n0 = blockIdx.y * 256;

  // stage mapping: linear LDS dest tid*16B (+8KB), inverse-swizzled source
  const int sp = tid >> 3;
  const int sv = (tid & 7) ^ (sp & 7);
  const int srow = 2 * sp + (sv >> 2);  // 0..127 (second load: +128)
  const int scol = (sv & 3) * 8;
  const int sdst = tid * 8;  // fp16 units within a 16KB half region

  // read mapping
  const int rp = r15 >> 1, rsub = r15 & 1;
  const int rslot = ((rsub * 4 + g) ^ rp) * 8;

  const float* Af = (const float*)A;
  const _Float16* Ah = (const _Float16*)A;

  f32x4 acc[8][4] = {};
  float4 fr0[4], fr1[4];
  half8 af[4], bf[4];

#define A_REGION(buf, kh) (&SH[(buf)*16384 + (kh)*8192])
#define B_REGION(buf, kh) (&SH[32768 + (buf)*16384 + (kh)*8192])

#define STAGE_B(t, buf, kh)                                                    \
  do {                                                                         \
    const _Float16* _s = Bw + (size_t)(n0 + srow) * K + (t)*64 + (kh)*32 + scol; \
    gload16(_s, B_REGION(buf, kh) + sdst);                                     \
    gload16(_s + (size_t)128 * K, B_REGION(buf, kh) + sdst + 4096);            \
  } while (0)

#define STAGE_A16(t, buf, kh)                                                  \
  do {                                                                         \
    const _Float16* _s = Ah + (size_t)(m0 + srow) * K + (t)*64 + (kh)*32 + scol; \
    gload16(_s, A_REGION(buf, kh) + sdst);                                     \
    gload16(_s + (size_t)128 * K, A_REGION(buf, kh) + sdst + 4096);            \
  } while (0)

#define A_ISSUE(fr, t, kh)                                                     \
  do {                                                                         \
    const float* _s = Af + (size_t)(m0 + srow) * K + (t)*64 + (kh)*32 + scol;  \
    fr[0] = ((const float4*)_s)[0];                                            \
    fr[1] = ((const float4*)_s)[1];                                            \
    const float* _s2 = _s + (size_t)128 * K;                                   \
    fr[2] = ((const float4*)_s2)[0];                                           \
    fr[3] = ((const float4*)_s2)[1];                                           \
  } while (0)

#define A_WRITE(fr, buf, kh)                                                   \
  do {                                                                         \
    *(half8*)&A_REGION(buf, kh)[sdst] = cvt8(fr[0], fr[1]);                    \
    *(half8*)&A_REGION(buf, kh)[sdst + 4096] = cvt8(fr[2], fr[3]);             \
  } while (0)

#define READ_AF(buf, kk, MH)                                                   \
  do {                                                                         \
    _Float16* _b = A_REGION(buf, kk);                                          \
    int _pb = (wr * 64 + (MH)*32 + rp) * 64 + rslot;                           \
    af[0] = *(half8*)&_b[_pb];                                                 \
    af[1] = *(half8*)&_b[_pb + 512];                                           \
    af[2] = *(half8*)&_b[_pb + 1024];                                          \
    af[3] = *(half8*)&_b[_pb + 1536];                                          \
  } while (0)

#define READ_BF(buf, kk)                                                       \
  do {                                                                         \
    _Float16* _b = B_REGION(buf, kk);                                          \
    int _pb = (wc * 32 + rp) * 64 + rslot;                                     \
    bf[0] = *(half8*)&_b[_pb];                                                 \
    bf[1] = *(half8*)&_b[_pb + 512];                                           \
    bf[2] = *(half8*)&_b[_pb + 1024];                                          \
    bf[3] = *(half8*)&_b[_pb + 1536];                                          \
  } while (0)

#define MFMA_Q(MH)                                                             \
  do {                                                                         \
    __builtin_amdgcn_s_setprio(1);                                             \
    _Pragma("unroll") for (int mi = 0; mi < 4; mi++)                           \
        _Pragma("unroll") for (int ni = 0; ni < 4; ni++) acc[(MH)*4 + mi][ni] = \
        MFMA16(af[mi], bf[ni], acc[(MH)*4 + mi][ni]);                          \
    __builtin_amdgcn_s_setprio(0);                                             \
  } while (0)

  // ---- prologue: stage tile 0 into buf 0
  if (A_F32) {
    A_ISSUE(fr0, 0, 0);
    A_ISSUE(fr1, 0, 1);
    STAGE_B(0, 0, 0);
    STAGE_B(0, 0, 1);
    VM(8); SCHED0;
    A_WRITE(fr0, 0, 0);
    VM(4); SCHED0;
    A_WRITE(fr1, 0, 1);
    asm volatile("s_waitcnt lgkmcnt(0)" ::: "memory");
  } else {
    STAGE_A16(0, 0, 0);
    STAGE_A16(0, 0, 1);
    STAGE_B(0, 0, 0);
    STAGE_B(0, 0, 1);
  }

  // ---- main loop: compute tile t (buf), stage tile t+1 (buf^1)
  for (int t = 0; t < NT - 1; t++) {
    const int buf = t & 1, nb = buf ^ 1;
    // phase 0: (kk0, mh0)  [needs t.A.kh0 (barrier t.p0), t.B.kh0]
    if (A_F32) {
      A_ISSUE(fr0, t + 1, 0);
      VM(6);  // queue: [t.B0|t.B1|A0-regs]; drain t.B0 and older
    } else {
      STAGE_A16(t + 1, nb, 0);
      VM(4);  // queue: [t.B0|t.B1|t+1.A0]; drain t.B0 and older
    }
    BARW;
    READ_AF(buf, 0, 0);
    READ_BF(buf, 0);
    LGKM0;
    MFMA_Q(0);
    // phase 1: (kk0, mh1)
    if (A_F32) A_ISSUE(fr1, t + 1, 1);
    else STAGE_A16(t + 1, nb, 1);
    READ_AF(buf, 0, 1);
    LGKM0;
    MFMA_Q(1);
    // phase 2: (kk1, mh0)  [needs t.B.kh1; proj: write t+1.A.kh0]
    STAGE_B(t + 1, nb, 0);
    VM(6); SCHED0;  // drain t.B1 (and A0-regs for proj)
    if (A_F32) A_WRITE(fr0, nb, 0);
    BARW;
    READ_AF(buf, 1, 0);
    READ_BF(buf, 1);
    LGKM0;
    MFMA_Q(0);
    // phase 3: (kk1, mh1)  [proj: write t+1.A.kh1]
    STAGE_B(t + 1, nb, 1);
    if (A_F32) {
      VM(4); SCHED0;  // drain A1-regs; allow t+1.B0,B1 flying
      A_WRITE(fr1, nb, 1);
    }
    READ_AF(buf, 1, 1);
    LGKM0;
    MFMA_Q(1);
  }

  // ---- tail: tile 15 (buf 1), no staging
  {
    VM(2);
    BARW;
    READ_AF(1, 0, 0);
    READ_BF(1, 0);
    LGKM0;
    MFMA_Q(0);
    READ_AF(1, 0, 1);
    LGKM0;
    MFMA_Q(1);
    VM(0);
    BARW;
    READ_AF(1, 1, 0);
    READ_BF(1, 1);
    LGKM0;
    MFMA_Q(0);
    READ_AF(1, 1, 1);
    LGKM0;
    MFMA_Q(1);
  }

  // ---- epilogue: D layout col = lane&15, row = (lane>>4)*4 + reg
#pragma unroll
  for (int ni = 0; ni < 4; ni++) {
    const int col = n0 + wc * 64 + ni * 16 + r15;
    const float bv = bias[col];
#pragma unroll
    for (int mi8 = 0; mi8 < 8; mi8++) {
      const int rowb = m0 + wr * 128 + mi8 * 16 + g * 4;
#pragma unroll
      for (int r = 0; r < 4; r++) {
        float x = acc[mi8][ni][r] + bv;
        if (OUT_F32)
          ((float*)Cout)[(size_t)(rowb + r) * NN + col] = x;
        else
          ((_Float16*)Cout)[(size_t)(rowb + r) * NN + col] = (_Float16)x;
      }
    }
  }
#undef A_REGION
#undef B_REGION
#undef STAGE_B
#undef STAGE_A16
#undef A_ISSUE
#undef A_WRITE
#undef READ_AF
#undef READ_BF
#undef MFMA_Q
}

// merged q/k/v projection: blockIdx.z selects input/weight/bias/output
__global__ __launch_bounds__(512) void gemm_proj_k(
    const float* __restrict__ Aq, const float* __restrict__ Ak,
    const float* __restrict__ Av, const _Float16* __restrict__ W16,
    const float* __restrict__ bq, const float* __restrict__ bk,
    const float* __restrict__ bv, _Float16* __restrict__ Oq,
    _Float16* __restrict__ Ok, _Float16* __restrict__ Ov) {
  const int z = blockIdx.z;
  const float* A = z == 0 ? Aq : z == 1 ? Ak : Av;
  const float* bias = z == 0 ? bq : z == 1 ? bk : bv;
  _Float16* out = z == 0 ? Oq : z == 1 ? Ok : Ov;
  gemm8p_body<1, 0>((const void*)A, W16 + ((size_t)z << 20), bias, (void*)out);
}

__global__ __launch_bounds__(512) void gemm_out_k(const _Float16* __restrict__ A,
                                                  const _Float16* __restrict__ Bw,
                                                  const float* __restrict__ bias,
                                                  float* __restrict__ Cout) {
  gemm8p_body<0, 1>((const void*)A, Bw, bias, (void*)Cout);
}

// ---------------- V transpose: Vp(L,B,E) -> Vt[(b*512+c)*64 + d][256 k] ----------------
__global__ __launch_bounds__(256) void vtrans_k(const _Float16* __restrict__ Vp,
                                                _Float16* __restrict__ Vt) {
  const int c = blockIdx.x, b = blockIdx.y;
  __shared__ alignas(16) _Float16 Vl[256 * 64];  // [k][d], chunk ^= k&7
  const int tid = threadIdx.x;
  const int l0 = c * 16;
#pragma unroll
  for (int i = 0; i < 8; i++) {
    int q = tid + i * 256;
    int w = q >> 3, ck = q & 7;
    int ls = l0 + (w >> 4), h = w & 15;
    half8 v = *(const half8*)(Vp + (size_t)(ls * 2 + b) * 1024 + h * 64 + ck * 8);
    *(half8*)&Vl[w * 64 + (ck ^ (w & 7)) * 8] = v;
  }
  __syncthreads();
  const int d = tid >> 2, kcq = tid & 3;
  const size_t obase = ((size_t)(b * 512 + c) * 64 + d) * 256 + kcq * 64;
#pragma unroll
  for (int i8 = 0; i8 < 8; i8++) {
    half8 v;
#pragma unroll
    for (int j = 0; j < 8; j++) {
      int k = kcq * 64 + i8 * 8 + j;
      v[j] = Vl[k * 64 + (((d >> 3) ^ (k & 7)) * 8) + (d & 7)];
    }
    *(half8*)(Vt + obase + i8 * 8) = v;
  }
}

// ---------------- window attention ----------------
__global__ __launch_bounds__(512) void attn_win_k(const _Float16* __restrict__ Qp,
                                                  const _Float16* __restrict__ Kp,
                                                  const _Float16* __restrict__ Vt,
                                                  _Float16* __restrict__ Y) {
  const int c = blockIdx.x, b = blockIdx.y;
  __shared__ alignas(16) _Float16 Kl[256 * 64];  // [k][d] swz chunk^=k&7; later P
  __shared__ alignas(16) _Float16 Vl[64 * 256];  // [d][k] swz chunk^=((d&7)<<2)
  const int tid = threadIdx.x, lane = tid & 63, wave = tid >> 6;
  const int i15 = lane & 15, g = lane >> 4;
  const int l0 = c * 16;

#pragma unroll
  for (int i = 0; i < 4; i++) {
    int q = tid + i * 512;
    int w = q >> 3, ck = q & 7;
    int ls = l0 + (w >> 4), h = w & 15;
    half8 v = *(const half8*)(Kp + (size_t)(ls * 2 + b) * 1024 + h * 64 + ck * 8);
    *(half8*)&Kl[w * 64 + (ck ^ (w & 7)) * 8] = v;
  }
  const size_t vb0 = (size_t)(b * 512 + c) * 64 * 256;
#pragma unroll
  for (int i = 0; i < 4; i++) {
    int q = tid + i * 512;
    int d = q >> 5, ck = q & 31;
    half8 v = *(const half8*)(Vt + vb0 + (size_t)d * 256 + ck * 8);
    *(half8*)&Vl[d * 256 + (ck ^ ((d & 7) << 2)) * 8] = v;
  }
  half8 qf[2][2];
#pragma unroll
  for (int wf = 0; wf < 2; wf++)
#pragma unroll
    for (int dh = 0; dh < 2; dh++) {
      int ls = l0 + wave * 2 + wf;
      qf[wf][dh] =
          *(const half8*)(Qp + (size_t)(ls * 2 + b) * 1024 + i15 * 64 + dh * 32 + g * 8);
    }
  __syncthreads();

  f32x4 acc[16][2] = {};
#pragma unroll
  for (int m = 0; m < 16; m++) {
    int row = m * 16 + i15;
    half8 a0 = *(half8*)&Kl[row * 64 + ((g) ^ (i15 & 7)) * 8];
    half8 a1 = *(half8*)&Kl[row * 64 + ((4 + g) ^ (i15 & 7)) * 8];
    acc[m][0] = MFMA16(a0, qf[0][0], acc[m][0]);
    acc[m][0] = MFMA16(a1, qf[0][1], acc[m][0]);
    acc[m][1] = MFMA16(a0, qf[1][0], acc[m][1]);
    acc[m][1] = MFMA16(a1, qf[1][1], acc[m][1]);
  }

#pragma unroll
  for (int wf = 0; wf < 2; wf++) {
    float mx = -3.0e38f;
#pragma unroll
    for (int m = 0; m < 16; m++)
#pragma unroll
      for (int r = 0; r < 4; r++) mx = fmaxf(mx, acc[m][wf][r]);
    mx = fmaxf(mx, __shfl_xor(mx, 16, 64));
    mx = fmaxf(mx, __shfl_xor(mx, 32, 64));
    float sum = 0.f;
#pragma unroll
    for (int m = 0; m < 16; m++)
#pragma unroll
      for (int r = 0; r < 4; r++) {
        float e = __expf((acc[m][wf][r] - mx) * 0.125f);
        acc[m][wf][r] = e;
        sum += e;
      }
    sum += __shfl_xor(sum, 16, 64);
    sum += __shfl_xor(sum, 32, 64);
    float inv = 1.f / sum;
#pragma unroll
    for (int m = 0; m < 16; m++)
#pragma unroll
      for (int r = 0; r < 4; r++) acc[m][wf][r] *= inv;
  }
  __syncthreads();

  _Float16* Pw = &Kl[wave * 2048];  // [32 rows][64 k] fp16, chunk ^= row&7
  f32x4 oacc[2][4] = {};
#pragma unroll
  for (int kq = 0; kq < 4; kq++) {
#pragma unroll
    for (int wf = 0; wf < 2; wf++) {
      int rrow = wf * 16 + i15;
#pragma unroll
      for (int ml = 0; ml < 4; ml++) {
        f32x4 pv = acc[kq * 4 + ml][wf];
        half4 h = {(_Float16)pv[0], (_Float16)pv[1], (_Float16)pv[2], (_Float16)pv[3]};
        int ck = ml * 2 + (g >> 1);
        *(half4*)&Pw[rrow * 64 + ((ck ^ (i15 & 7)) * 8) + (g & 1) * 4] = h;
      }
    }
    asm volatile("s_waitcnt lgkmcnt(0)" ::: "memory");
    __builtin_amdgcn_sched_barrier(0);
#pragma unroll
    for (int kfl = 0; kfl < 2; kfl++) {
      half8 pa0 = *(half8*)&Pw[(i15)*64 + (((kfl * 4 + g) ^ (i15 & 7)) * 8)];
      half8 pa1 = *(half8*)&Pw[(16 + i15) * 64 + (((kfl * 4 + g) ^ (i15 & 7)) * 8)];
#pragma unroll
      for (int df = 0; df < 4; df++) {
        int drow = df * 16 + i15;
        half8 vbf =
            *(half8*)&Vl[drow * 256 + (((kq * 8 + kfl * 4 + g) ^ ((i15 & 7) << 2)) * 8)];
        oacc[0][df] = MFMA16(pa0, vbf, oacc[0][df]);
        oacc[1][df] = MFMA16(pa1, vbf, oacc[1][df]);
      }
    }
  }

  const int h2 = c >> 5, n = c & 31;
  const size_t yb = ((size_t)(h2 * 2 + b) * 8192 + (size_t)n * 256) * 64;
#pragma unroll
  for (int wf = 0; wf < 2; wf++)
#pragma unroll
    for (int df = 0; df < 4; df++)
#pragma unroll
      for (int r = 0; r < 4; r++) {
        int w = wave * 32 + wf * 16 + g * 4 + r;
        Y[yb + (size_t)w * 64 + df * 16 + i15] = (_Float16)oacc[wf][df][r];
      }
}

// ---------------- launch ----------------
extern "C" void kernel_launch(void* const* d_in, const int* in_sizes, int n_in,
                              void* d_out, int out_size, void* d_ws, size_t ws_size,
                              hipStream_t stream) {
  const float* query = (const float*)d_in[0];
  const float* key_ = (const float*)d_in[1];
  const float* value = (const float*)d_in[2];
  const float* Wq = (const float*)d_in[3];
  const float* bq = (const float*)d_in[4];
  const float* Wk = (const float*)d_in[5];
  const float* bk = (const float*)d_in[6];
  const float* Wv = (const float*)d_in[7];
  const float* bv = (const float*)d_in[8];
  const float* Wo = (const float*)d_in[9];
  const float* bo = (const float*)d_in[10];

  _Float16* ws = (_Float16*)d_ws;
  _Float16* W16 = ws;                // 4 x 1M halves (8 MB): q,k,v,o
  _Float16* W16o = W16 + 3 * (1 << 20);
  _Float16* Vp = ws + 4 * (1 << 20); // 16M halves (32 MB): V proj, later Ybuf
  _Float16* Vt = Vp + (1 << 24);     // 16M halves (32 MB)
  _Float16* Ybuf = Vp;               // alias: Vp dead after vtrans

  _Float16* Qp = (_Float16*)d_out;   // Q,K projections parked in d_out
  _Float16* Kp = Qp + (1 << 24);

  cvtw_k<<<dim3(512, 4), 256, 0, stream>>>(Wq, Wk, Wv, Wo, W16);

  gemm_proj_k<<<dim3(64, 4, 3), 512, 0, stream>>>(query, key_, value, W16, bq, bk, bv,
                                                  Qp, Kp, Vp);

  vtrans_k<<<dim3(512, 2), 256, 0, stream>>>(Vp, Vt);
  attn_win_k<<<dim3(512, 2), 512, 0, stream>>>(Qp, Kp, Vt, Ybuf);

  gemm_out_k<<<dim3(64, 4), 512, 0, stream>>>(Ybuf, W16o, bo, (float*)d_out);

  (void)in_sizes; (void)n_in; (void)out_size; (void)ws_size;
}